// Round 7
// baseline (1030.231 us; speedup 1.0000x reference)
//
#include <hip/hip_runtime.h>
#include <hip/hip_bf16.h>

#define N_ROWS 100000
#define T_DIM  512
#define DIN    256
#define DH     256
#define KC     800
#define NSTEP  25      // KC / 32
#define NCHUNK 125     // 125 * 800 = 100000 exactly

typedef __attribute__((ext_vector_type(8))) short s16x8;
typedef __attribute__((ext_vector_type(4))) float f32x4;

// pack two f32 into bf16 pair (RTNE), low = lo, high = hi
static __device__ __forceinline__ unsigned bf16pair(float lo, float hi) {
  unsigned a = __builtin_bit_cast(unsigned, lo);
  unsigned b = __builtin_bit_cast(unsigned, hi);
  a = (a + 0x7fffu + ((a >> 16) & 1u)) >> 16;
  b = (b + 0x7fffu + ((b >> 16) & 1u)) & 0xffff0000u;
  return a | b;
}

// ---------------- Kernel 1: ve = H^T @ X as dense bf16 MFMA GEMM, split-K ----
__global__ __launch_bounds__(512, 2) void k_agg_mfma(
    const float* __restrict__ X, const float* __restrict__ Hm,
    float* __restrict__ ve, float* __restrict__ ve_part, int use_part)
{
  __shared__ unsigned smem[8192];   // A: [0,4096) u32, B: [4096,8192) ; 32 KB
  const int tid  = threadIdx.x;
  const int mt   = blockIdx.x & 1;
  const int kc   = blockIdx.x >> 1;
  const int m0   = mt * 256;
  const int k0   = kc * KC;
  const int lane = tid & 63;
  const int wv   = tid >> 6;        // 8 waves: 2 (wm) x 4 (wn)
  const int wm   = wv >> 2, wn = wv & 3;

  f32x4 acc[8][4] = {};

  const int kp0 = tid >> 6;
  const int kp1 = kp0 + 8;
  const int gg  = tid & 63;

  float4 ra0, ra1, ra2, ra3, rb0, rb1, rb2, rb3;

  auto load_tile = [&](int kt) {
    const size_t kb = (size_t)(k0 + kt * 32);
    const float* pa0 = &Hm[(kb + 2 * kp0) * T_DIM + m0 + gg * 4];
    ra0 = *(const float4*)pa0;
    ra1 = *(const float4*)(pa0 + T_DIM);
    const float* pa1 = &Hm[(kb + 2 * kp1) * T_DIM + m0 + gg * 4];
    ra2 = *(const float4*)pa1;
    ra3 = *(const float4*)(pa1 + T_DIM);
    const float* pb0 = &X[(kb + 2 * kp0) * DIN + gg * 4];
    rb0 = *(const float4*)pb0;
    rb1 = *(const float4*)(pb0 + DIN);
    const float* pb1 = &X[(kb + 2 * kp1) * DIN + gg * 4];
    rb2 = *(const float4*)pb1;
    rb3 = *(const float4*)(pb1 + DIN);
  };

  auto store_tile = [&]() {
#pragma unroll
    for (int d = 0; d < 4; ++d) {
      const int m  = gg * 4 + d;
      const int sw = d << 2;
      smem[m * 16 + (kp0 ^ sw)]        = bf16pair(((const float*)&ra0)[d], ((const float*)&ra1)[d]);
      smem[m * 16 + (kp1 ^ sw)]        = bf16pair(((const float*)&ra2)[d], ((const float*)&ra3)[d]);
      smem[4096 + m * 16 + (kp0 ^ sw)] = bf16pair(((const float*)&rb0)[d], ((const float*)&rb1)[d]);
      smem[4096 + m * 16 + (kp1 ^ sw)] = bf16pair(((const float*)&rb2)[d], ((const float*)&rb3)[d]);
    }
  };

  auto compute = [&]() {
    const uint4* sv = (const uint4*)smem;
    s16x8 af[8], bfr[4];
#pragma unroll
    for (int fm = 0; fm < 8; ++fm) {
      const int m = wm * 128 + fm * 16 + (lane & 15);
      af[fm] = __builtin_bit_cast(s16x8, sv[m * 4 + ((lane >> 4) ^ (m & 3))]);
    }
#pragma unroll
    for (int fn = 0; fn < 4; ++fn) {
      const int n = wn * 64 + fn * 16 + (lane & 15);
      bfr[fn] = __builtin_bit_cast(s16x8, sv[1024 + n * 4 + ((lane >> 4) ^ (n & 3))]);
    }
#pragma unroll
    for (int fm = 0; fm < 8; ++fm)
#pragma unroll
      for (int fn = 0; fn < 4; ++fn)
        acc[fm][fn] = __builtin_amdgcn_mfma_f32_16x16x32_bf16(af[fm], bfr[fn], acc[fm][fn], 0, 0, 0);
  };

  load_tile(0);
  store_tile();
  for (int kt = 0; kt < NSTEP; ++kt) {
    __syncthreads();
    if (kt + 1 < NSTEP) load_tile(kt + 1);
    compute();
    __syncthreads();
    if (kt + 1 < NSTEP) store_tile();
  }

  if (use_part) {
    float* dst = ve_part + (size_t)kc * (512 * 256);
#pragma unroll
    for (int fm = 0; fm < 8; ++fm) {
      const int r0 = m0 + wm * 128 + fm * 16 + (lane >> 4) * 4;
#pragma unroll
      for (int fn = 0; fn < 4; ++fn) {
        const int cc = wn * 64 + fn * 16 + (lane & 15);
#pragma unroll
        for (int q = 0; q < 4; ++q)
          dst[(size_t)(r0 + q) * 256 + cc] = acc[fm][fn][q];
      }
    }
  } else {
#pragma unroll
    for (int fm = 0; fm < 8; ++fm) {
      const int r0 = m0 + wm * 128 + fm * 16 + (lane >> 4) * 4;
#pragma unroll
      for (int fn = 0; fn < 4; ++fn) {
        const int cc = wn * 64 + fn * 16 + (lane & 15);
#pragma unroll
        for (int q = 0; q < 4; ++q)
          atomicAdd(&ve[(size_t)(r0 + q) * 256 + cc], acc[fm][fn][q]);
      }
    }
  }
}

// ---------------- Kernel 2: reduce split-K partials + gx = ve @ W_ih^T + b ----
__global__ __launch_bounds__(256) void k_gx(
    const float* __restrict__ vesrc, int npart,
    const float* __restrict__ Wih, const float* __restrict__ bih,
    float* __restrict__ gx)
{
  __shared__ float vl[DIN];
  const int t = blockIdx.x, j = threadIdx.x;
  float s = 0.f;
  for (int p = 0; p < npart; ++p) s += vesrc[(size_t)p * (512 * 256) + t * DIN + j];
  vl[j] = s;
  __syncthreads();
  float a0 = bih[j], a1 = bih[256 + j], a2 = bih[512 + j];
  const float* __restrict__ w0 = &Wih[(size_t)j * DIN];
  const float* __restrict__ w1 = &Wih[(size_t)(j + 256) * DIN];
  const float* __restrict__ w2 = &Wih[(size_t)(j + 512) * DIN];
#pragma unroll 4
  for (int k = 0; k < DIN; ++k) {
    const float v = vl[k];
    a0 = fmaf(w0[k], v, a0);
    a1 = fmaf(w1[k], v, a1);
    a2 = fmaf(w2[k], v, a2);
  }
  gx[t * 768 + j]       = a0;
  gx[t * 768 + 256 + j] = a1;
  gx[t * 768 + 512 + j] = a2;
}

// ---------------- Kernel 3: GRU scan via MFMA matvec + attention -------------
// EXACT R5 structure/source (proven absmax 2.44e-3) with ONE change:
// amdgpu_waves_per_eu(2,2). R5's RA targeted 4 waves/SIMD (128-reg budget) and
// spilled the 192-reg wf[] to SCRATCH (~3600cy/step). Pinning max waves = 2
// raises the budget to 256; overflow now spills to AGPRs (1-cy copies).
// R6 lesson: inline-asm MFMA is opaque to the backend hazard recognizer ->
// silent numerical corruption; builtins get mandatory wait-states inserted.
__global__ __launch_bounds__(512, 2) __attribute__((amdgpu_waves_per_eu(2, 2)))
void k_gru_att(
    const float* __restrict__ Whh, const float* __restrict__ bhh,
    const float* __restrict__ gx, const float* __restrict__ watt,
    float* __restrict__ hs, float* __restrict__ out)
{
  __shared__ __hip_bfloat16 hb[DH];   // h_{t-1} as bf16 (512 B)
  __shared__ float ghs[768];          // gh + bias rows
  __shared__ float bsh[768];          // staged b_hh (acc init); reused as partials
  __shared__ float sc[T_DIM];
  __shared__ float red[2];

  const int tid = threadIdx.x;
  const int w   = tid >> 6;
  const int l   = tid & 63;
  const int lr  = l & 15;   // row within 16-tile
  const int lg  = l >> 4;   // k-group / row-quad selector

  int rowbase[6];
  rowbase[0] = w * 32;       rowbase[1] = w * 32 + 16;
  rowbase[2] = 256 + w * 32; rowbase[3] = 256 + w * 32 + 16;
  rowbase[4] = 512 + w * 32; rowbase[5] = 512 + w * 32 + 16;

  // Weight fragments: A[m=lr][k = kb*32 + lg*8 + 0..7] per lane.
  s16x8 wf[6][8];
#pragma unroll
  for (int tt = 0; tt < 6; ++tt) {
    const float* rp = &Whh[(size_t)(rowbase[tt] + lr) * DH + lg * 8];
#pragma unroll
    for (int kb = 0; kb < 8; ++kb) {
      const float4 x0 = *(const float4*)(rp + kb * 32);
      const float4 x1 = *(const float4*)(rp + kb * 32 + 4);
      uint4 uu;
      uu.x = bf16pair(x0.x, x0.y);
      uu.y = bf16pair(x0.z, x0.w);
      uu.z = bf16pair(x1.x, x1.y);
      uu.w = bf16pair(x1.z, x1.w);
      wf[tt][kb] = __builtin_bit_cast(s16x8, uu);
    }
  }

  bsh[tid] = bhh[tid < 768 ? tid : 0];
  if (tid < 256) {
    bsh[512 + tid] = bhh[512 + tid];
    hb[tid] = __float2bfloat16(0.0f);
  }
  float h = 0.f;
  __syncthreads();

  for (int t = 0; t < T_DIM; ++t) {
    // prefetch gx for this step; consumed after the MFMA phase (hides latency)
    float gxr = 0.f, gxz = 0.f, gxn = 0.f;
    if (tid < 256) {
      gxr = gx[t * 768 + tid];
      gxz = gx[t * 768 + 256 + tid];
      gxn = gx[t * 768 + 512 + tid];
    }
    // acc init = b_hh rows (bias folded into gh)
    f32x4 acc[6];
#pragma unroll
    for (int tt = 0; tt < 6; ++tt)
      acc[tt] = *(const f32x4*)&bsh[rowbase[tt] + lg * 4];
    // B fragment: h[k = kb*32 + lg*8 + 0..7], same for all 16 cols
#pragma unroll
    for (int kb = 0; kb < 8; ++kb) {
      const s16x8 bf = *(const s16x8*)((const char*)hb + kb * 64 + lg * 16);
#pragma unroll
      for (int tt = 0; tt < 6; ++tt)
        acc[tt] = __builtin_amdgcn_mfma_f32_16x16x32_bf16(wf[tt][kb], bf, acc[tt], 0, 0, 0);
    }
    // write gh rows: C row = lg*4+q, all cols identical -> lanes lr==0 publish
    if (lr == 0) {
#pragma unroll
      for (int tt = 0; tt < 6; ++tt)
        *(f32x4*)&ghs[rowbase[tt] + lg * 4] = acc[tt];
    }
    __syncthreads();              // gh visible; also: all hb reads of step t done
    if (tid < 256) {
      const float r = 1.f / (1.f + __expf(-(gxr + ghs[tid])));
      const float z = 1.f / (1.f + __expf(-(gxz + ghs[256 + tid])));
      const float pn = gxn + r * ghs[512 + tid];
      const float n = 2.f / (1.f + __expf(-2.f * pn)) - 1.f;   // tanh
      h = (1.f - z) * n + z * h;
      hs[t * DH + tid] = h;
      hb[tid] = __float2bfloat16(h);
    }
    __syncthreads();              // h_t visible for step t+1
  }

  // ---- attention epilogue: alpha = softmax(hs @ w_att); out = alpha^T hs ----
  {
    const float* __restrict__ hr = &hs[tid * DH];
    float s = 0.f;
#pragma unroll 4
    for (int k = 0; k < DH; k += 4) {
      const float4 hv = *(const float4*)(hr + k);
      const float4 wv4 = *(const float4*)(watt + k);
      s = fmaf(hv.x, wv4.x, s); s = fmaf(hv.y, wv4.y, s);
      s = fmaf(hv.z, wv4.z, s); s = fmaf(hv.w, wv4.w, s);
    }
    sc[tid] = s;
  }
  __syncthreads();
  if (tid < 64) {
    float m = -1e30f;
#pragma unroll
    for (int i = 0; i < 8; ++i) m = fmaxf(m, sc[tid * 8 + i]);
#pragma unroll
    for (int off = 32; off > 0; off >>= 1) m = fmaxf(m, __shfl_down(m, off));
    if (tid == 0) red[0] = m;
  }
  __syncthreads();
  const float M = red[0];
  sc[tid] = __expf(sc[tid] - M);
  __syncthreads();
  if (tid < 64) {
    float s = 0.f;
#pragma unroll
    for (int i = 0; i < 8; ++i) s += sc[tid * 8 + i];
#pragma unroll
    for (int off = 32; off > 0; off >>= 1) s += __shfl_down(s, off);
    if (tid == 0) red[1] = s;
  }
  __syncthreads();
  const float inv = 1.f / red[1];
  // weighted sum: two half-ranges of t in parallel, partials in bsh
  {
    const int j = tid & 255, half = tid >> 8;
    float acc = 0.f;
    for (int t = half * 256; t < half * 256 + 256; ++t)
      acc = fmaf(sc[t], hs[t * DH + j], acc);
    bsh[half * 256 + j] = acc;
  }
  __syncthreads();
  if (tid < 256) out[tid] = (bsh[tid] + bsh[256 + tid]) * inv;
}

extern "C" void kernel_launch(void* const* d_in, const int* in_sizes, int n_in,
                              void* d_out, int out_size, void* d_ws, size_t ws_size,
                              hipStream_t stream) {
  const float* X    = (const float*)d_in[0];
  const float* H    = (const float*)d_in[1];
  const float* Wih  = (const float*)d_in[2];
  const float* Whh  = (const float*)d_in[3];
  const float* bih  = (const float*)d_in[4];
  const float* bhh  = (const float*)d_in[5];
  const float* watt = (const float*)d_in[6];
  float* out = (float*)d_out;

  char* ws = (char*)d_ws;
  float* gx      = (float*)ws;                        // 512*768*4 = 1572864 B
  float* hs      = (float*)(ws + 1572864);            // 512*256*4 = 524288 B
  float* ve      = (float*)(ws + 2097152);            // 524288 B (atomic fallback)
  float* ve_part = (float*)(ws + 2621440);            // 125*512*256*4 = 65536000 B

  const size_t need_part = 2621440 + 65536000;
  const int use_part = (ws_size >= need_part) ? 1 : 0;

  if (!use_part)
    hipMemsetAsync(ve, 0, T_DIM * DIN * sizeof(float), stream);

  k_agg_mfma<<<2 * NCHUNK, 512, 0, stream>>>(X, H, ve, ve_part, use_part);
  k_gx<<<T_DIM, 256, 0, stream>>>(use_part ? ve_part : ve, use_part ? NCHUNK : 1,
                                  Wih, bih, gx);
  k_gru_att<<<1, 512, 0, stream>>>(Whh, bhh, gx, watt, hs, out);
}

// Round 8
// 999.416 us; speedup vs baseline: 1.0308x; 1.0308x over previous
//
#include <hip/hip_runtime.h>
#include <hip/hip_bf16.h>

#define N_ROWS 100000
#define T_DIM  512
#define DIN    256
#define DH     256
#define KC     800
#define NSTEP  25      // KC / 32
#define NCHUNK 125     // 125 * 800 = 100000 exactly

typedef __attribute__((ext_vector_type(8))) short s16x8;
typedef __attribute__((ext_vector_type(4))) float f32x4;

// pack two f32 into bf16 pair (RTNE), low = lo, high = hi
static __device__ __forceinline__ unsigned bf16pair(float lo, float hi) {
  unsigned a = __builtin_bit_cast(unsigned, lo);
  unsigned b = __builtin_bit_cast(unsigned, hi);
  a = (a + 0x7fffu + ((a >> 16) & 1u)) >> 16;
  b = (b + 0x7fffu + ((b >> 16) & 1u)) & 0xffff0000u;
  return a | b;
}

// ---------------- Kernel 1: ve = H^T @ X as dense bf16 MFMA GEMM, split-K ----
__global__ __launch_bounds__(512, 2) void k_agg_mfma(
    const float* __restrict__ X, const float* __restrict__ Hm,
    float* __restrict__ ve, float* __restrict__ ve_part, int use_part)
{
  __shared__ unsigned smem[8192];   // A: [0,4096) u32, B: [4096,8192) ; 32 KB
  const int tid  = threadIdx.x;
  const int mt   = blockIdx.x & 1;
  const int kc   = blockIdx.x >> 1;
  const int m0   = mt * 256;
  const int k0   = kc * KC;
  const int lane = tid & 63;
  const int wv   = tid >> 6;        // 8 waves: 2 (wm) x 4 (wn)
  const int wm   = wv >> 2, wn = wv & 3;

  f32x4 acc[8][4] = {};

  const int kp0 = tid >> 6;
  const int kp1 = kp0 + 8;
  const int gg  = tid & 63;

  float4 ra0, ra1, ra2, ra3, rb0, rb1, rb2, rb3;

  auto load_tile = [&](int kt) {
    const size_t kb = (size_t)(k0 + kt * 32);
    const float* pa0 = &Hm[(kb + 2 * kp0) * T_DIM + m0 + gg * 4];
    ra0 = *(const float4*)pa0;
    ra1 = *(const float4*)(pa0 + T_DIM);
    const float* pa1 = &Hm[(kb + 2 * kp1) * T_DIM + m0 + gg * 4];
    ra2 = *(const float4*)pa1;
    ra3 = *(const float4*)(pa1 + T_DIM);
    const float* pb0 = &X[(kb + 2 * kp0) * DIN + gg * 4];
    rb0 = *(const float4*)pb0;
    rb1 = *(const float4*)(pb0 + DIN);
    const float* pb1 = &X[(kb + 2 * kp1) * DIN + gg * 4];
    rb2 = *(const float4*)pb1;
    rb3 = *(const float4*)(pb1 + DIN);
  };

  auto store_tile = [&]() {
#pragma unroll
    for (int d = 0; d < 4; ++d) {
      const int m  = gg * 4 + d;
      const int sw = d << 2;
      smem[m * 16 + (kp0 ^ sw)]        = bf16pair(((const float*)&ra0)[d], ((const float*)&ra1)[d]);
      smem[m * 16 + (kp1 ^ sw)]        = bf16pair(((const float*)&ra2)[d], ((const float*)&ra3)[d]);
      smem[4096 + m * 16 + (kp0 ^ sw)] = bf16pair(((const float*)&rb0)[d], ((const float*)&rb1)[d]);
      smem[4096 + m * 16 + (kp1 ^ sw)] = bf16pair(((const float*)&rb2)[d], ((const float*)&rb3)[d]);
    }
  };

  auto compute = [&]() {
    const uint4* sv = (const uint4*)smem;
    s16x8 af[8], bfr[4];
#pragma unroll
    for (int fm = 0; fm < 8; ++fm) {
      const int m = wm * 128 + fm * 16 + (lane & 15);
      af[fm] = __builtin_bit_cast(s16x8, sv[m * 4 + ((lane >> 4) ^ (m & 3))]);
    }
#pragma unroll
    for (int fn = 0; fn < 4; ++fn) {
      const int n = wn * 64 + fn * 16 + (lane & 15);
      bfr[fn] = __builtin_bit_cast(s16x8, sv[1024 + n * 4 + ((lane >> 4) ^ (n & 3))]);
    }
#pragma unroll
    for (int fm = 0; fm < 8; ++fm)
#pragma unroll
      for (int fn = 0; fn < 4; ++fn)
        acc[fm][fn] = __builtin_amdgcn_mfma_f32_16x16x32_bf16(af[fm], bfr[fn], acc[fm][fn], 0, 0, 0);
  };

  load_tile(0);
  store_tile();
  for (int kt = 0; kt < NSTEP; ++kt) {
    __syncthreads();
    if (kt + 1 < NSTEP) load_tile(kt + 1);
    compute();
    __syncthreads();
    if (kt + 1 < NSTEP) store_tile();
  }

  if (use_part) {
    float* dst = ve_part + (size_t)kc * (512 * 256);
#pragma unroll
    for (int fm = 0; fm < 8; ++fm) {
      const int r0 = m0 + wm * 128 + fm * 16 + (lane >> 4) * 4;
#pragma unroll
      for (int fn = 0; fn < 4; ++fn) {
        const int cc = wn * 64 + fn * 16 + (lane & 15);
#pragma unroll
        for (int q = 0; q < 4; ++q)
          dst[(size_t)(r0 + q) * 256 + cc] = acc[fm][fn][q];
      }
    }
  } else {
#pragma unroll
    for (int fm = 0; fm < 8; ++fm) {
      const int r0 = m0 + wm * 128 + fm * 16 + (lane >> 4) * 4;
#pragma unroll
      for (int fn = 0; fn < 4; ++fn) {
        const int cc = wn * 64 + fn * 16 + (lane & 15);
#pragma unroll
        for (int q = 0; q < 4; ++q)
          atomicAdd(&ve[(size_t)(r0 + q) * 256 + cc], acc[fm][fn][q]);
      }
    }
  }
}

// ---------------- Kernel 2: reduce split-K partials + gx = ve @ W_ih^T + b ----
__global__ __launch_bounds__(256) void k_gx(
    const float* __restrict__ vesrc, int npart,
    const float* __restrict__ Wih, const float* __restrict__ bih,
    float* __restrict__ gx)
{
  __shared__ float vl[DIN];
  const int t = blockIdx.x, j = threadIdx.x;
  float s = 0.f;
  for (int p = 0; p < npart; ++p) s += vesrc[(size_t)p * (512 * 256) + t * DIN + j];
  vl[j] = s;
  __syncthreads();
  float a0 = bih[j], a1 = bih[256 + j], a2 = bih[512 + j];
  const float* __restrict__ w0 = &Wih[(size_t)j * DIN];
  const float* __restrict__ w1 = &Wih[(size_t)(j + 256) * DIN];
  const float* __restrict__ w2 = &Wih[(size_t)(j + 512) * DIN];
#pragma unroll 4
  for (int k = 0; k < DIN; ++k) {
    const float v = vl[k];
    a0 = fmaf(w0[k], v, a0);
    a1 = fmaf(w1[k], v, a1);
    a2 = fmaf(w2[k], v, a2);
  }
  gx[t * 768 + j]       = a0;
  gx[t * 768 + 256 + j] = a1;
  gx[t * 768 + 512 + j] = a2;
}

// ---------------- Kernel 3: GRU scan via MFMA matvec + attention -------------
// 1024 threads = 16 waves = 4 waves/SIMD — the 128-reg budget the allocator
// demonstrably targets (R5/R7 both allocated 128). Wave w owns 48 rows of W_hh
// (rows w*16..+16 of each gate) = 3 tiles x 8 k-blocks = 96 VGPRs of weight
// fragments + 12 acc + ~20 temps ~= 125 <= 128 -> NO SPILL (R5/R7 spilled
// 192-reg wf to scratch, ~245KB/step re-read = 1.5us/step). Only waves-per-eu
// source is amdgpu_waves_per_eu(4,4); launch_bounds has no 2nd arg (R7 lesson:
// launch_bounds' own waves-per-eu=min overrides the explicit attribute).
__global__ __launch_bounds__(1024) __attribute__((amdgpu_waves_per_eu(4, 4)))
void k_gru_att(
    const float* __restrict__ Whh, const float* __restrict__ bhh,
    const float* __restrict__ gx, const float* __restrict__ watt,
    float* __restrict__ hs, float* __restrict__ out)
{
  __shared__ __hip_bfloat16 hb[DH];   // h_{t-1} as bf16 (512 B)
  __shared__ float ghs[768];          // gh + bias rows
  __shared__ float bsh[768];          // staged b_hh (acc init)
  __shared__ float sc[T_DIM];
  __shared__ float part[1024];        // attention partials
  __shared__ float red[2];

  const int tid = threadIdx.x;
  const int w   = tid >> 6;   // wave 0..15
  const int l   = tid & 63;
  const int lr  = l & 15;     // row within 16-tile
  const int lg  = l >> 4;     // k-group / row-quad selector

  // wave w, tile tt -> rows [tt*256 + w*16, +16)  (tile tt == gate tt)
  int rowbase[3];
  rowbase[0] = w * 16;
  rowbase[1] = 256 + w * 16;
  rowbase[2] = 512 + w * 16;

  // Weight fragments: A[m=lr][k = kb*32 + lg*8 + 0..7] per lane. 96 VGPRs.
  s16x8 wf[3][8];
#pragma unroll
  for (int tt = 0; tt < 3; ++tt) {
    const float* rp = &Whh[(size_t)(rowbase[tt] + lr) * DH + lg * 8];
#pragma unroll
    for (int kb = 0; kb < 8; ++kb) {
      const float4 x0 = *(const float4*)(rp + kb * 32);
      const float4 x1 = *(const float4*)(rp + kb * 32 + 4);
      uint4 uu;
      uu.x = bf16pair(x0.x, x0.y);
      uu.y = bf16pair(x0.z, x0.w);
      uu.z = bf16pair(x1.x, x1.y);
      uu.w = bf16pair(x1.z, x1.w);
      wf[tt][kb] = __builtin_bit_cast(s16x8, uu);
    }
  }

  if (tid < 768) bsh[tid] = bhh[tid];
  if (tid < 256) hb[tid] = __float2bfloat16(0.0f);
  float h = 0.f;
  __syncthreads();

  for (int t = 0; t < T_DIM; ++t) {
    // prefetch gx for this step; consumed after the MFMA phase (hides latency)
    float gxr = 0.f, gxz = 0.f, gxn = 0.f;
    if (tid < 256) {
      gxr = gx[t * 768 + tid];
      gxz = gx[t * 768 + 256 + tid];
      gxn = gx[t * 768 + 512 + tid];
    }
    // acc init = b_hh rows (bias folded into gh)
    f32x4 acc[3];
#pragma unroll
    for (int tt = 0; tt < 3; ++tt)
      acc[tt] = *(const f32x4*)&bsh[rowbase[tt] + lg * 4];
    // B fragment: h[k = kb*32 + lg*8 + 0..7], same for all 16 cols
#pragma unroll
    for (int kb = 0; kb < 8; ++kb) {
      const s16x8 bf = *(const s16x8*)((const char*)hb + kb * 64 + lg * 16);
#pragma unroll
      for (int tt = 0; tt < 3; ++tt)
        acc[tt] = __builtin_amdgcn_mfma_f32_16x16x32_bf16(wf[tt][kb], bf, acc[tt], 0, 0, 0);
    }
    // write gh rows: C row = lg*4+q, all cols identical -> lanes lr==0 publish
    if (lr == 0) {
#pragma unroll
      for (int tt = 0; tt < 3; ++tt)
        *(f32x4*)&ghs[rowbase[tt] + lg * 4] = acc[tt];
    }
    __syncthreads();              // gh visible; also: all hb reads of step t done
    if (tid < 256) {
      const float r = 1.f / (1.f + __expf(-(gxr + ghs[tid])));
      const float z = 1.f / (1.f + __expf(-(gxz + ghs[256 + tid])));
      const float pn = gxn + r * ghs[512 + tid];
      const float n = 2.f / (1.f + __expf(-2.f * pn)) - 1.f;   // tanh
      h = (1.f - z) * n + z * h;
      hs[t * DH + tid] = h;
      hb[tid] = __float2bfloat16(h);
    }
    __syncthreads();              // h_t visible for step t+1
  }

  // ---- attention epilogue: alpha = softmax(hs @ w_att); out = alpha^T hs ----
  if (tid < T_DIM) {
    const float* __restrict__ hr = &hs[tid * DH];
    float s = 0.f;
#pragma unroll 4
    for (int k = 0; k < DH; k += 4) {
      const float4 hv = *(const float4*)(hr + k);
      const float4 wv4 = *(const float4*)(watt + k);
      s = fmaf(hv.x, wv4.x, s); s = fmaf(hv.y, wv4.y, s);
      s = fmaf(hv.z, wv4.z, s); s = fmaf(hv.w, wv4.w, s);
    }
    sc[tid] = s;
  }
  __syncthreads();
  if (tid < 64) {
    float m = -1e30f;
#pragma unroll
    for (int i = 0; i < 8; ++i) m = fmaxf(m, sc[tid * 8 + i]);
#pragma unroll
    for (int off = 32; off > 0; off >>= 1) m = fmaxf(m, __shfl_down(m, off));
    if (tid == 0) red[0] = m;
  }
  __syncthreads();
  const float M = red[0];
  if (tid < T_DIM) sc[tid] = __expf(sc[tid] - M);
  __syncthreads();
  if (tid < 64) {
    float s = 0.f;
#pragma unroll
    for (int i = 0; i < 8; ++i) s += sc[tid * 8 + i];
#pragma unroll
    for (int off = 32; off > 0; off >>= 1) s += __shfl_down(s, off);
    if (tid == 0) red[1] = s;
  }
  __syncthreads();
  const float inv = 1.f / red[1];
  // weighted sum: four quarter-ranges of t in parallel, partials in part[]
  {
    const int j = tid & 255, q = tid >> 8;
    float acc = 0.f;
    for (int t = q * 128; t < q * 128 + 128; ++t)
      acc = fmaf(sc[t], hs[t * DH + j], acc);
    part[q * 256 + j] = acc;
  }
  __syncthreads();
  if (tid < 256)
    out[tid] = (part[tid] + part[256 + tid] + part[512 + tid] + part[768 + tid]) * inv;
}

extern "C" void kernel_launch(void* const* d_in, const int* in_sizes, int n_in,
                              void* d_out, int out_size, void* d_ws, size_t ws_size,
                              hipStream_t stream) {
  const float* X    = (const float*)d_in[0];
  const float* H    = (const float*)d_in[1];
  const float* Wih  = (const float*)d_in[2];
  const float* Whh  = (const float*)d_in[3];
  const float* bih  = (const float*)d_in[4];
  const float* bhh  = (const float*)d_in[5];
  const float* watt = (const float*)d_in[6];
  float* out = (float*)d_out;

  char* ws = (char*)d_ws;
  float* gx      = (float*)ws;                        // 512*768*4 = 1572864 B
  float* hs      = (float*)(ws + 1572864);            // 512*256*4 = 524288 B
  float* ve      = (float*)(ws + 2097152);            // 524288 B (atomic fallback)
  float* ve_part = (float*)(ws + 2621440);            // 125*512*256*4 = 65536000 B

  const size_t need_part = 2621440 + 65536000;
  const int use_part = (ws_size >= need_part) ? 1 : 0;

  if (!use_part)
    hipMemsetAsync(ve, 0, T_DIM * DIN * sizeof(float), stream);

  k_agg_mfma<<<2 * NCHUNK, 512, 0, stream>>>(X, H, ve, ve_part, use_part);
  k_gx<<<T_DIM, 256, 0, stream>>>(use_part ? ve_part : ve, use_part ? NCHUNK : 1,
                                  Wih, bih, gx);
  k_gru_att<<<1, 1024, 0, stream>>>(Whh, bhh, gx, watt, hs, out);
}